// Round 1
// baseline (190.868 us; speedup 1.0000x reference)
//
#include <hip/hip_runtime.h>

// RGCN encoder, MI355X.  out[n] = sum_r (c[n][r]/cnt[n]) * (emb[n]@W2[r] + b2[r])
// (only layer-2 live; messages scatter to their own source node).
// Round-11 EXPERIMENT: go 100% workspace-free. The rocprof top-5 is entirely
// harness fillBuffer dispatches (256 MiB d_ws re-poison @43.5us each) and both
// our kernels are <43.4us, so at least one poison fill sits inside the timed
// window. This round:
//   (1) scatter segments+counts live inside d_out: bucket b's scratch is in
//       tile b's OWN 64KB output region (stride-40-ushort segs: 38 entries +
//       count at slot 39 -> 512*80B = 40960B, exactly the truncated last
//       tile's 160 rows). Main block b reads only its own region, overwrites
//       it only at the final store (ordered by the histogram __syncthreads).
//   (2) bf16 weight/bias fragments live in __device__ module globals
//       (harness can't poison those; prep rewrites them every launch).
//   (3) riders: scatter LDS 42KB (3 blocks/CU), main gather unpacks uint
//       pairs (half the gather load instructions).
// GEMM r-loop (soft s_barrier L1-aligned weight streaming) unchanged.

typedef float  floatx4 __attribute__((ext_vector_type(4)));
typedef short  shortx8 __attribute__((ext_vector_type(8)));
typedef unsigned int uint;
typedef unsigned char uchar;

#define MFMA_BF16(A, B, C) __builtin_amdgcn_mfma_f32_16x16x32_bf16((A), (B), (C), 0, 0, 0)

#define NBUF 512        // scatter writer blocks
#define NBKT 512        // max buckets (391 used at N=100000)
#define CAP  38         // u16 entries per (writer,bucket); load ~Poisson(10), P(>38)~3e-12
#define SEGW 40         // ushort stride per segment: [0..37]=entries, [39]=count
#define BROW 40         // LDS bin row stride (4B-aligned uint reads)
#define PREPB 19        // 18 weight-transpose blocks + 1 bias block

// module-static scratch: persists across iterations, rewritten every launch,
// NOT part of d_ws so the harness poison never touches it.
__device__ ushort wt_g[73728];   // bf16 [18][4096] fragment order
__device__ ushort bias_g[2048];  // bf16 fragment order

static __device__ __forceinline__ ushort f32_to_bf16_rne(float f) {
    union { float f; unsigned u; } v; v.f = f;
    unsigned r = v.u + 0x7fffu + ((v.u >> 16) & 1u);
    return (ushort)(r >> 16);
}

// ---- dispatch 1: scatter (blocks 0..NBUF) + prep (blocks NBUF..NBUF+PREPB)
// prep fragment layout: wt_g[r*4096 + d], d=(cid*64+lane)*8+j encodes
//   nt=cid>>1, kh=cid&1, o=nt*16+(lane&15), k=kh*32+(lane>>4)*8+j,
//   value = bf16(W2[r][k][o])
__global__ __launch_bounds__(256) void rgcn_scatter_prep(
    const int*   __restrict__ ei,       // [2][E]
    const int*   __restrict__ et,       // [E]
    const float* __restrict__ w2,       // fp32 [18][64][64]
    const float* __restrict__ b2,       // fp32 [18][64]
    float*       __restrict__ out,      // scratch target: tile-own regions
    int E, int N, int nbuckets)
{
    __shared__ uint   cur[NBKT];
    __shared__ ushort bins[NBKT][BROW];  // 40 KB (rows 4B-aligned; overlaid as wlds for prep)

    const int t = threadIdx.x;

    if (blockIdx.x >= NBUF) {            // ---- prep part -> device globals
        int pb = blockIdx.x - NBUF;
        ushort* wlds = &bins[0][0];      // reuse LDS: 4096 bf16 = 8 KB
        if (pb < 18) {
            // coalesced read of W2[pb] (4096 floats), bf16 into LDS at [k*64+o]
            const float* src = w2 + (pb << 12);
            #pragma unroll
            for (int i = 0; i < 16; i++) {
                int idx = t + 256 * i;
                wlds[idx] = f32_to_bf16_rne(src[idx]);
            }
            __syncthreads();
            // coalesced write: thread t emits d = t*16 .. t*16+15
            ushort* dst = wt_g + (pb << 12);
            #pragma unroll
            for (int u = 0; u < 16; u++) {
                int d = t * 16 + u;
                int cid  = d >> 9;
                int lane = (d >> 3) & 63;
                int j    = d & 7;
                int o = (cid >> 1) * 16 + (lane & 15);
                int k = (cid & 1) * 32 + (lane >> 4) * 8 + j;
                dst[d] = wlds[(k << 6) + o];
            }
        } else {
            // bias: bias_g[i2], o=nt*16+(lane&15), rr=(lane>>4)*8+j
            #pragma unroll
            for (int u = 0; u < 8; u++) {
                int i2 = t * 8 + u;
                int nt   = i2 >> 9;
                int lane = (i2 >> 3) & 63;
                int j    = i2 & 7;
                int o  = nt * 16 + (lane & 15);
                int rr = (lane >> 4) * 8 + j;
                bias_g[i2] = (rr < 18) ? f32_to_bf16_rne(b2[rr * 64 + o]) : (ushort)0;
            }
        }
        return;
    }

    // ---- scatter part
    #pragma unroll
    for (int b = t; b < NBKT; b += 256) cur[b] = 0;
    __syncthreads();

    const int epb = (E + NBUF - 1) / NBUF;
    const int e0 = blockIdx.x * epb;
    const int e1 = (e0 + epb < E) ? e0 + epb : E;

    for (int e = e0 + t; e < e1; e += 256) {
        int r = et[e]; int i0 = ei[e]; int i1 = ei[E + e];
        if ((unsigned)r < 9u) {
            if ((unsigned)i0 < (unsigned)N) {
                int b = i0 >> 8;
                uint o = atomicAdd(&cur[b], 1u);
                if (o < CAP) bins[b][o] = (ushort)((i0 & 255) * 18 + r);
            }
            if ((unsigned)i1 < (unsigned)N) {
                int b = i1 >> 8;
                uint o = atomicAdd(&cur[b], 1u);
                if (o < CAP) bins[b][o] = (ushort)((i1 & 255) * 18 + 9 + r);
            }
        }
    }
    __syncthreads();

    // compacted flush into tile-own regions of out:
    //   seg(b,blk) = out + b*65536B + blk*80B ; entries [0..c-1], count at u16[39]
    const int blk = blockIdx.x;
    for (int b = t; b < nbuckets; b += 256) {
        uint c = cur[b];
        if (c > CAP) c = CAP;
        ushort* seg = (ushort*)((char*)out + (size_t)b * 65536 + (size_t)blk * (SEGW * 2));
        uint words = (c + 1) >> 1;
        uint* dst = (uint*)seg;
        const uint* srcp = (const uint*)&bins[b][0];
        for (uint wd = 0; wd < words; wd++) dst[wd] = srcp[wd];
        seg[SEGW - 1] = (ushort)c;
    }
}

// ---- fallback path kernels (shape doesn't fit tile-own scratch): ws-based
__global__ void rgcn_prep_k(const float* __restrict__ w2, const float* __restrict__ b2,
                            ushort* __restrict__ wt_sw, ushort* __restrict__ bias_sw) {
    int i = blockIdx.x * 256 + threadIdx.x;
    const int WELEMS = 18 * 8 * 64 * 8;
    if (i < WELEMS) {
        int r    = i >> 12;
        int rem  = i & 4095;
        int cid  = rem >> 9;
        int lane = (rem >> 3) & 63;
        int j    = i & 7;
        int nt = cid >> 1, kh = cid & 1;
        int o = nt * 16 + (lane & 15);
        int k = kh * 32 + (lane >> 4) * 8 + j;
        wt_sw[i] = f32_to_bf16_rne(w2[(r << 12) + (k << 6) + o]);
    } else {
        int i2 = i - WELEMS;
        if (i2 < 2048) {
            int nt   = i2 >> 9;
            int lane = (i2 >> 3) & 63;
            int j    = i2 & 7;
            int o  = nt * 16 + (lane & 15);
            int rr = (lane >> 4) * 8 + j;
            bias_sw[i2] = (rr < 18) ? f32_to_bf16_rne(b2[rr * 64 + o]) : (ushort)0;
        }
    }
}
__global__ void rgcn_count32(const int* __restrict__ ei, const int* __restrict__ et,
                             int* __restrict__ cnts, int E, int N) {
    int e = blockIdx.x * 256 + threadIdx.x;
    if (e < E) {
        int r = et[e];
        int i0 = ei[e];
        int i1 = ei[E + e];
        if ((unsigned)r < 9u) {
            if ((unsigned)i0 < (unsigned)N) atomicAdd(&cnts[i0 * 18 + r], 1);
            if ((unsigned)i1 < (unsigned)N) atomicAdd(&cnts[i1 * 18 + 9 + r], 1);
        }
    }
}
__global__ void rgcn_cvt8(const int* __restrict__ c32, uchar* __restrict__ c8, int total4) {
    int i = blockIdx.x * 256 + threadIdx.x;
    if (i < total4) {
        uint v = 0;
        #pragma unroll
        for (int j = 0; j < 4; j++) {
            int c = c32[i * 4 + j];
            if (c > 255) c = 255;
            v |= ((uint)c) << (8 * j);
        }
        ((uint*)c8)[i] = v;
    }
}

static __device__ __forceinline__ void load_af(
    const float* __restrict__ emb, int n, int q, shortx8 af[2])
{
    const float* rp = emb + (size_t)n * 64 + q * 8;
    #pragma unroll
    for (int kh = 0; kh < 2; kh++) {
        floatx4 lo = *(const floatx4*)(rp + kh * 32);
        floatx4 hi = *(const floatx4*)(rp + kh * 32 + 4);
        shortx8 f;
        #pragma unroll
        for (int j = 0; j < 4; j++) {
            f[j]     = (short)f32_to_bf16_rne(lo[j]);
            f[j + 4] = (short)f32_to_bf16_rne(hi[j]);
        }
        af[kh] = f;
    }
}

// shared GEMM tail: r-loop with SOFT wave-alignment barriers + bias MFMA + store
static __device__ __forceinline__ void gemm_store(
    const shortx8 af[4][2],
    const float  (*__restrict__ wft)[256],
    const ushort (*__restrict__ wbL)[32],
    const ushort* __restrict__ wbase,
    const ushort* __restrict__ bias_p,
    float* __restrict__ out, int N,
    int lrow, int rowbase, int m, int q, int lane)
{
    shortx8 bA[8], bB[8];
    #pragma unroll
    for (int c = 0; c < 8; c++) bA[c] = *(const shortx8*)(wbase + c * 512);

    floatx4 acc[4][4];
    #pragma unroll
    for (int mt = 0; mt < 4; mt++)
        #pragma unroll
        for (int nt = 0; nt < 4; nt++)
            acc[mt][nt] = (floatx4){0.f, 0.f, 0.f, 0.f};

    for (int r = 0; r < 18; r += 2) {
        // SOFT barrier: bare s_barrier (no waitcnt drain) — aligns the 4 waves
        // so they stream the same 8KB/r weight chunk through L1 together.
        __builtin_amdgcn_s_barrier();
        {   // prefetch r+1
            const ushort* p = wbase + (size_t)(r + 1) * 4096;
            #pragma unroll
            for (int c = 0; c < 8; c++) bB[c] = *(const shortx8*)(p + c * 512);
        }
        {   // compute r
            floatx4 swv[4];
            #pragma unroll
            for (int mt = 0; mt < 4; mt++)
                swv[mt] = *(const floatx4*)&wft[r][lrow + mt * 16 + q * 4];
            #pragma unroll
            for (int nt = 0; nt < 4; nt++)
                #pragma unroll
                for (int mt = 0; mt < 4; mt++) {
                    floatx4 tmp = (floatx4){0.f, 0.f, 0.f, 0.f};
                    tmp = MFMA_BF16(af[mt][0], bA[nt * 2 + 0], tmp);
                    tmp = MFMA_BF16(af[mt][1], bA[nt * 2 + 1], tmp);
                    acc[mt][nt] += swv[mt] * tmp;
                }
        }
        if (r + 2 < 18) {   // prefetch r+2
            const ushort* p = wbase + (size_t)(r + 2) * 4096;
            #pragma unroll
            for (int c = 0; c < 8; c++) bA[c] = *(const shortx8*)(p + c * 512);
        }
        {   // compute r+1
            floatx4 swv[4];
            #pragma unroll
            for (int mt = 0; mt < 4; mt++)
                swv[mt] = *(const floatx4*)&wft[r + 1][lrow + mt * 16 + q * 4];
            #pragma unroll
            for (int nt = 0; nt < 4; nt++)
                #pragma unroll
                for (int mt = 0; mt < 4; mt++) {
                    floatx4 tmp = (floatx4){0.f, 0.f, 0.f, 0.f};
                    tmp = MFMA_BF16(af[mt][0], bB[nt * 2 + 0], tmp);
                    tmp = MFMA_BF16(af[mt][1], bB[nt * 2 + 1], tmp);
                    acc[mt][nt] += swv[mt] * tmp;
                }
        }
    }

    // bias MFMA: A = w-hat bf16 rows (K=32), B = bias fragments
    #pragma unroll
    for (int nt = 0; nt < 4; nt++) {
        shortx8 btf = *(const shortx8*)(bias_p + ((size_t)nt * 64 + lane) * 8);
        #pragma unroll
        for (int mt = 0; mt < 4; mt++) {
            shortx8 wfrag = *(const shortx8*)&wbL[lrow + mt * 16 + m][q * 8];
            acc[mt][nt] = MFMA_BF16(wfrag, btf, acc[mt][nt]);
        }
    }

    // store; D layout col = nt*16+m, row = q*4+i
    #pragma unroll
    for (int mt = 0; mt < 4; mt++)
        #pragma unroll
        for (int i = 0; i < 4; i++) {
            int nn = rowbase + mt * 16 + q * 4 + i;
            if (nn < N) {
                #pragma unroll
                for (int nt = 0; nt < 4; nt++)
                    out[(size_t)nn * 64 + nt * 16 + m] = acc[mt][nt][i];
            }
        }
}

// ---- dispatch 2: fused bucket-count + w-hat + GEMM. One block per 256-node tile.
// Reads its OWN tile region of out (scratch written by dispatch 1), then
// overwrites it with the final rows. No other block touches this region.
__global__ __launch_bounds__(256, 2) void rgcn_main(
    const float*  __restrict__ emb,      // fp32 [N][64]
    float*        out,                   // fp32 [N][64]; first 40960B/tile = scratch
    int N)
{
    __shared__ int    cnt[4608];      // 18 KB: per-key counts for this tile
    __shared__ float  wft[18][256];   // 18 KB: w-hat transposed
    __shared__ ushort wbL[256][32];   // 16 KB: bf16 w-hat (k-padded)

    const int t    = threadIdx.x;
    const int b    = blockIdx.x;
    const int wave = t >> 6;
    const int lane = t & 63;
    const int m    = lane & 15;
    const int q    = lane >> 4;
    const int rowbase = b * 256 + wave * 64;
    const int lrow    = wave * 64;

    #pragma unroll
    for (int i = t; i < 4608; i += 256) cnt[i] = 0;

    // A fragments + first weight prefetch before the barrier (global,
    // independent of LDS) so their latency overlaps phase-A setup
    shortx8 af[4][2];
    #pragma unroll
    for (int mt = 0; mt < 4; mt++) {
        int n = rowbase + mt * 16 + m;
        if (n >= N) n = N - 1;           // contribution zeroed via w-hat=0
        load_af(emb, n, q, af[mt]);
    }
    const ushort* wbase = &wt_g[0] + (size_t)lane * 8;

    __syncthreads();   // cnt zeroed

    // gather this tile's compacted segments (own region) + LDS histogram
    const ushort* reg = (const ushort*)((const char*)out + (size_t)b * 65536);
    #pragma unroll
    for (int w = t; w < NBUF; w += 256) {
        const ushort* seg = reg + w * SEGW;
        uint c = seg[SEGW - 1];
        const uint* sw = (const uint*)seg;
        for (uint wd = 0; wd < (c >> 1); wd++) {
            uint v = sw[wd];
            atomicAdd(&cnt[v & 0xffffu], 1);
            atomicAdd(&cnt[v >> 16], 1);
        }
        if (c & 1) atomicAdd(&cnt[seg[c - 1]], 1);
    }
    __syncthreads();   // histogram done (also drains all scratch reads)

    // per-node normalized relation weights (thread t <-> local node t)
    {
        int c[18]; int s = 0;
        #pragma unroll
        for (int r = 0; r < 18; r++) { c[r] = cnt[t * 18 + r]; s += c[r]; }
        float inv = (s > 0) ? (1.0f / (float)s) : 0.0f;
        #pragma unroll
        for (int r = 0; r < 18; r++) {
            float w = (float)c[r] * inv;
            wft[r][t] = w;
            wbL[t][r] = f32_to_bf16_rne(w);
        }
        #pragma unroll
        for (int r = 18; r < 32; r++) wbL[t][r] = 0;
    }
    __syncthreads();   // wft/wbL ready — last hard barrier

    gemm_store(af, wft, wbL, wbase, &bias_g[0], out, N, lrow, rowbase, m, q, lane);
}

// ---- fallback main: reads packed u8 counts (used only for odd shapes)
__global__ __launch_bounds__(256, 2) void rgcn_main_c8(
    const float*  __restrict__ emb,
    const uchar*  __restrict__ cnts8,    // [nbuckets][4608]
    const ushort* __restrict__ wt_sw,
    const ushort* __restrict__ bias_sw,
    float*        __restrict__ out,
    int N)
{
    __shared__ float  wft[18][256];
    __shared__ ushort wbL[256][32];
    __shared__ uchar  craw[4608];

    const int t    = threadIdx.x;
    const int wave = t >> 6;
    const int lane = t & 63;
    const int m    = lane & 15;
    const int q    = lane >> 4;
    const int rowbase = blockIdx.x * 256 + wave * 64;
    const int lrow    = wave * 64;

    {
        const uint* srcp = (const uint*)(cnts8 + (size_t)blockIdx.x * 4608);
        uint* d = (uint*)craw;
        #pragma unroll
        for (int i = t; i < 1152; i += 256) d[i] = srcp[i];
    }
    shortx8 af[4][2];
    #pragma unroll
    for (int mt = 0; mt < 4; mt++) {
        int n = rowbase + mt * 16 + m;
        if (n >= N) n = N - 1;
        load_af(emb, n, q, af[mt]);
    }
    const ushort* wbase = wt_sw + (size_t)lane * 8;
    __syncthreads();
    {
        int c[18]; int s = 0;
        const uchar* cp = &craw[t * 18];
        #pragma unroll
        for (int r = 0; r < 18; r++) { c[r] = cp[r]; s += c[r]; }
        float inv = (s > 0) ? (1.0f / (float)s) : 0.0f;
        #pragma unroll
        for (int r = 0; r < 18; r++) {
            float w = (float)c[r] * inv;
            wft[r][t] = w;
            wbL[t][r] = f32_to_bf16_rne(w);
        }
        #pragma unroll
        for (int r = 18; r < 32; r++) wbL[t][r] = 0;
    }
    __syncthreads();
    gemm_store(af, wft, wbL, wbase, bias_sw, out, N, lrow, rowbase, m, q, lane);
}

extern "C" void kernel_launch(void* const* d_in, const int* in_sizes, int n_in,
                              void* d_out, int out_size, void* d_ws, size_t ws_size,
                              hipStream_t stream) {
    const int*   edge_index = (const int*)d_in[0];     // [2][E] int32
    const int*   edge_type  = (const int*)d_in[1];     // [E]    int32
    const float* emb        = (const float*)d_in[2];   // [N][64]  fp32
    const float* weights    = (const float*)d_in[3];   // [3][18][64][64] fp32
    const float* biases     = (const float*)d_in[4];   // [3][18][64] fp32
    float* out = (float*)d_out;

    const int E = in_sizes[1];
    const int N = in_sizes[2] / 64;
    const int nbuckets = (N + 255) >> 8;               // 256-node tiles

    const float* w2 = weights + 2 * 18 * 64 * 64;      // only layer 2 is live
    const float* b2 = biases  + 2 * 18 * 64;

    // fast path needs: buckets fit the table AND the (possibly truncated)
    // last tile region holds its 512*80B of scratch
    const int lastrows = N - 256 * (nbuckets - 1);
    const bool fast = (nbuckets <= NBKT) &&
                      ((size_t)lastrows * 256 >= (size_t)NBUF * (SEGW * 2)) &&
                      ((size_t)out_size >= (size_t)N * 256);

    if (fast) {
        // ZERO workspace usage: scratch lives in d_out tile regions + device globals
        rgcn_scatter_prep<<<NBUF + PREPB, 256, 0, stream>>>(
            edge_index, edge_type, w2, b2, out, E, N, nbuckets);
        rgcn_main<<<nbuckets, 256, 0, stream>>>(emb, out, N);
    } else {
        // fallback: scattered atomics into i32, pack to u8, c8 main (ws-based)
        int* c32 = (int*)d_ws;
        uchar* cnts8 = (uchar*)((char*)d_ws + (((size_t)nbuckets * 4608 * 4 + 63) & ~(size_t)63));
        ushort* wt_sw   = (ushort*)(cnts8 + (size_t)nbuckets * 4608);
        ushort* bias_sw = wt_sw + 73728;
        rgcn_prep_k<<<(73728 + 2048 + 255) / 256, 256, 0, stream>>>(w2, b2, wt_sw, bias_sw);
        hipMemsetAsync(c32, 0, (size_t)nbuckets * 4608 * 4, stream);
        rgcn_count32<<<(E + 255) / 256, 256, 0, stream>>>(edge_index, edge_type, c32, E, N);
        int total4 = nbuckets * 4608 / 4;
        rgcn_cvt8<<<(total4 + 255) / 256, 256, 0, stream>>>(c32, cnts8, total4);
        rgcn_main_c8<<<nbuckets, 256, 0, stream>>>(emb, cnts8, wt_sw, bias_sw, out, N);
    }
}

// Round 2
// 124.750 us; speedup vs baseline: 1.5300x; 1.5300x over previous
//
#include <hip/hip_runtime.h>

// RGCN encoder, MI355X.  out[n] = sum_r (c[n][r]/cnt[n]) * (emb[n]@W2[r] + b2[r])
// (only layer-2 live; messages scatter to their own source node).
// Round-12: FIX the fast-path gate. Round-11's ws-free experiment never ran:
// out_size is an ELEMENT count (like in_sizes[]), so `out_size >= N*256`
// (bytes) was false -> fallback path (count32 @78.8us visible in profile,
// dur 191us). Gate now units-agnostic: out_size >= N*64 holds for both
// elements (6.4M) and bytes (25.6M). Kernels otherwise byte-identical:
//   (1) scatter segments+counts live inside d_out tile-own regions
//       (512 x 80B per tile = 40960B, fits the truncated 160-row last tile).
//   (2) bf16 weight/bias fragments in __device__ module globals.
//   (3) main gathers via uint-pair unpack; GEMM r-loop (soft s_barrier
//       L1-aligned weight streaming) unchanged.

typedef float  floatx4 __attribute__((ext_vector_type(4)));
typedef short  shortx8 __attribute__((ext_vector_type(8)));
typedef unsigned int uint;
typedef unsigned char uchar;

#define MFMA_BF16(A, B, C) __builtin_amdgcn_mfma_f32_16x16x32_bf16((A), (B), (C), 0, 0, 0)

#define NBUF 512        // scatter writer blocks
#define NBKT 512        // max buckets (391 used at N=100000)
#define CAP  38         // u16 entries per (writer,bucket); load ~Poisson(10), P(>38)~3e-12
#define SEGW 40         // ushort stride per segment: [0..37]=entries, [39]=count
#define BROW 40         // LDS bin row stride (4B-aligned uint reads)
#define PREPB 19        // 18 weight-transpose blocks + 1 bias block

// module-static scratch: persists across iterations, rewritten every launch,
// NOT part of d_ws so the harness poison never touches it.
__device__ ushort wt_g[73728];   // bf16 [18][4096] fragment order
__device__ ushort bias_g[2048];  // bf16 fragment order

static __device__ __forceinline__ ushort f32_to_bf16_rne(float f) {
    union { float f; unsigned u; } v; v.f = f;
    unsigned r = v.u + 0x7fffu + ((v.u >> 16) & 1u);
    return (ushort)(r >> 16);
}

// ---- dispatch 1: scatter (blocks 0..NBUF) + prep (blocks NBUF..NBUF+PREPB)
// prep fragment layout: wt_g[r*4096 + d], d=(cid*64+lane)*8+j encodes
//   nt=cid>>1, kh=cid&1, o=nt*16+(lane&15), k=kh*32+(lane>>4)*8+j,
//   value = bf16(W2[r][k][o])
__global__ __launch_bounds__(256) void rgcn_scatter_prep(
    const int*   __restrict__ ei,       // [2][E]
    const int*   __restrict__ et,       // [E]
    const float* __restrict__ w2,       // fp32 [18][64][64]
    const float* __restrict__ b2,       // fp32 [18][64]
    float*       __restrict__ out,      // scratch target: tile-own regions
    int E, int N, int nbuckets)
{
    __shared__ uint   cur[NBKT];
    __shared__ ushort bins[NBKT][BROW];  // 40 KB (rows 4B-aligned; overlaid as wlds for prep)

    const int t = threadIdx.x;

    if (blockIdx.x >= NBUF) {            // ---- prep part -> device globals
        int pb = blockIdx.x - NBUF;
        ushort* wlds = &bins[0][0];      // reuse LDS: 4096 bf16 = 8 KB
        if (pb < 18) {
            // coalesced read of W2[pb] (4096 floats), bf16 into LDS at [k*64+o]
            const float* src = w2 + (pb << 12);
            #pragma unroll
            for (int i = 0; i < 16; i++) {
                int idx = t + 256 * i;
                wlds[idx] = f32_to_bf16_rne(src[idx]);
            }
            __syncthreads();
            // coalesced write: thread t emits d = t*16 .. t*16+15
            ushort* dst = wt_g + (pb << 12);
            #pragma unroll
            for (int u = 0; u < 16; u++) {
                int d = t * 16 + u;
                int cid  = d >> 9;
                int lane = (d >> 3) & 63;
                int j    = d & 7;
                int o = (cid >> 1) * 16 + (lane & 15);
                int k = (cid & 1) * 32 + (lane >> 4) * 8 + j;
                dst[d] = wlds[(k << 6) + o];
            }
        } else {
            // bias: bias_g[i2], o=nt*16+(lane&15), rr=(lane>>4)*8+j
            #pragma unroll
            for (int u = 0; u < 8; u++) {
                int i2 = t * 8 + u;
                int nt   = i2 >> 9;
                int lane = (i2 >> 3) & 63;
                int j    = i2 & 7;
                int o  = nt * 16 + (lane & 15);
                int rr = (lane >> 4) * 8 + j;
                bias_g[i2] = (rr < 18) ? f32_to_bf16_rne(b2[rr * 64 + o]) : (ushort)0;
            }
        }
        return;
    }

    // ---- scatter part
    #pragma unroll
    for (int b = t; b < NBKT; b += 256) cur[b] = 0;
    __syncthreads();

    const int epb = (E + NBUF - 1) / NBUF;
    const int e0 = blockIdx.x * epb;
    const int e1 = (e0 + epb < E) ? e0 + epb : E;

    for (int e = e0 + t; e < e1; e += 256) {
        int r = et[e]; int i0 = ei[e]; int i1 = ei[E + e];
        if ((unsigned)r < 9u) {
            if ((unsigned)i0 < (unsigned)N) {
                int b = i0 >> 8;
                uint o = atomicAdd(&cur[b], 1u);
                if (o < CAP) bins[b][o] = (ushort)((i0 & 255) * 18 + r);
            }
            if ((unsigned)i1 < (unsigned)N) {
                int b = i1 >> 8;
                uint o = atomicAdd(&cur[b], 1u);
                if (o < CAP) bins[b][o] = (ushort)((i1 & 255) * 18 + 9 + r);
            }
        }
    }
    __syncthreads();

    // compacted flush into tile-own regions of out:
    //   seg(b,blk) = out + b*65536B + blk*80B ; entries [0..c-1], count at u16[39]
    const int blk = blockIdx.x;
    for (int b = t; b < nbuckets; b += 256) {
        uint c = cur[b];
        if (c > CAP) c = CAP;
        ushort* seg = (ushort*)((char*)out + (size_t)b * 65536 + (size_t)blk * (SEGW * 2));
        uint words = (c + 1) >> 1;
        uint* dst = (uint*)seg;
        const uint* srcp = (const uint*)&bins[b][0];
        for (uint wd = 0; wd < words; wd++) dst[wd] = srcp[wd];
        seg[SEGW - 1] = (ushort)c;
    }
}

// ---- fallback path kernels (shape doesn't fit tile-own scratch): ws-based
__global__ void rgcn_prep_k(const float* __restrict__ w2, const float* __restrict__ b2,
                            ushort* __restrict__ wt_sw, ushort* __restrict__ bias_sw) {
    int i = blockIdx.x * 256 + threadIdx.x;
    const int WELEMS = 18 * 8 * 64 * 8;
    if (i < WELEMS) {
        int r    = i >> 12;
        int rem  = i & 4095;
        int cid  = rem >> 9;
        int lane = (rem >> 3) & 63;
        int j    = i & 7;
        int nt = cid >> 1, kh = cid & 1;
        int o = nt * 16 + (lane & 15);
        int k = kh * 32 + (lane >> 4) * 8 + j;
        wt_sw[i] = f32_to_bf16_rne(w2[(r << 12) + (k << 6) + o]);
    } else {
        int i2 = i - WELEMS;
        if (i2 < 2048) {
            int nt   = i2 >> 9;
            int lane = (i2 >> 3) & 63;
            int j    = i2 & 7;
            int o  = nt * 16 + (lane & 15);
            int rr = (lane >> 4) * 8 + j;
            bias_sw[i2] = (rr < 18) ? f32_to_bf16_rne(b2[rr * 64 + o]) : (ushort)0;
        }
    }
}
__global__ void rgcn_count32(const int* __restrict__ ei, const int* __restrict__ et,
                             int* __restrict__ cnts, int E, int N) {
    int e = blockIdx.x * 256 + threadIdx.x;
    if (e < E) {
        int r = et[e];
        int i0 = ei[e];
        int i1 = ei[E + e];
        if ((unsigned)r < 9u) {
            if ((unsigned)i0 < (unsigned)N) atomicAdd(&cnts[i0 * 18 + r], 1);
            if ((unsigned)i1 < (unsigned)N) atomicAdd(&cnts[i1 * 18 + 9 + r], 1);
        }
    }
}
__global__ void rgcn_cvt8(const int* __restrict__ c32, uchar* __restrict__ c8, int total4) {
    int i = blockIdx.x * 256 + threadIdx.x;
    if (i < total4) {
        uint v = 0;
        #pragma unroll
        for (int j = 0; j < 4; j++) {
            int c = c32[i * 4 + j];
            if (c > 255) c = 255;
            v |= ((uint)c) << (8 * j);
        }
        ((uint*)c8)[i] = v;
    }
}

static __device__ __forceinline__ void load_af(
    const float* __restrict__ emb, int n, int q, shortx8 af[2])
{
    const float* rp = emb + (size_t)n * 64 + q * 8;
    #pragma unroll
    for (int kh = 0; kh < 2; kh++) {
        floatx4 lo = *(const floatx4*)(rp + kh * 32);
        floatx4 hi = *(const floatx4*)(rp + kh * 32 + 4);
        shortx8 f;
        #pragma unroll
        for (int j = 0; j < 4; j++) {
            f[j]     = (short)f32_to_bf16_rne(lo[j]);
            f[j + 4] = (short)f32_to_bf16_rne(hi[j]);
        }
        af[kh] = f;
    }
}

// shared GEMM tail: r-loop with SOFT wave-alignment barriers + bias MFMA + store
static __device__ __forceinline__ void gemm_store(
    const shortx8 af[4][2],
    const float  (*__restrict__ wft)[256],
    const ushort (*__restrict__ wbL)[32],
    const ushort* __restrict__ wbase,
    const ushort* __restrict__ bias_p,
    float* __restrict__ out, int N,
    int lrow, int rowbase, int m, int q, int lane)
{
    shortx8 bA[8], bB[8];
    #pragma unroll
    for (int c = 0; c < 8; c++) bA[c] = *(const shortx8*)(wbase + c * 512);

    floatx4 acc[4][4];
    #pragma unroll
    for (int mt = 0; mt < 4; mt++)
        #pragma unroll
        for (int nt = 0; nt < 4; nt++)
            acc[mt][nt] = (floatx4){0.f, 0.f, 0.f, 0.f};

    for (int r = 0; r < 18; r += 2) {
        // SOFT barrier: bare s_barrier (no waitcnt drain) — aligns the 4 waves
        // so they stream the same 8KB/r weight chunk through L1 together.
        __builtin_amdgcn_s_barrier();
        {   // prefetch r+1
            const ushort* p = wbase + (size_t)(r + 1) * 4096;
            #pragma unroll
            for (int c = 0; c < 8; c++) bB[c] = *(const shortx8*)(p + c * 512);
        }
        {   // compute r
            floatx4 swv[4];
            #pragma unroll
            for (int mt = 0; mt < 4; mt++)
                swv[mt] = *(const floatx4*)&wft[r][lrow + mt * 16 + q * 4];
            #pragma unroll
            for (int nt = 0; nt < 4; nt++)
                #pragma unroll
                for (int mt = 0; mt < 4; mt++) {
                    floatx4 tmp = (floatx4){0.f, 0.f, 0.f, 0.f};
                    tmp = MFMA_BF16(af[mt][0], bA[nt * 2 + 0], tmp);
                    tmp = MFMA_BF16(af[mt][1], bA[nt * 2 + 1], tmp);
                    acc[mt][nt] += swv[mt] * tmp;
                }
        }
        if (r + 2 < 18) {   // prefetch r+2
            const ushort* p = wbase + (size_t)(r + 2) * 4096;
            #pragma unroll
            for (int c = 0; c < 8; c++) bA[c] = *(const shortx8*)(p + c * 512);
        }
        {   // compute r+1
            floatx4 swv[4];
            #pragma unroll
            for (int mt = 0; mt < 4; mt++)
                swv[mt] = *(const floatx4*)&wft[r + 1][lrow + mt * 16 + q * 4];
            #pragma unroll
            for (int nt = 0; nt < 4; nt++)
                #pragma unroll
                for (int mt = 0; mt < 4; mt++) {
                    floatx4 tmp = (floatx4){0.f, 0.f, 0.f, 0.f};
                    tmp = MFMA_BF16(af[mt][0], bB[nt * 2 + 0], tmp);
                    tmp = MFMA_BF16(af[mt][1], bB[nt * 2 + 1], tmp);
                    acc[mt][nt] += swv[mt] * tmp;
                }
        }
    }

    // bias MFMA: A = w-hat bf16 rows (K=32), B = bias fragments
    #pragma unroll
    for (int nt = 0; nt < 4; nt++) {
        shortx8 btf = *(const shortx8*)(bias_p + ((size_t)nt * 64 + lane) * 8);
        #pragma unroll
        for (int mt = 0; mt < 4; mt++) {
            shortx8 wfrag = *(const shortx8*)&wbL[lrow + mt * 16 + m][q * 8];
            acc[mt][nt] = MFMA_BF16(wfrag, btf, acc[mt][nt]);
        }
    }

    // store; D layout col = nt*16+m, row = q*4+i
    #pragma unroll
    for (int mt = 0; mt < 4; mt++)
        #pragma unroll
        for (int i = 0; i < 4; i++) {
            int nn = rowbase + mt * 16 + q * 4 + i;
            if (nn < N) {
                #pragma unroll
                for (int nt = 0; nt < 4; nt++)
                    out[(size_t)nn * 64 + nt * 16 + m] = acc[mt][nt][i];
            }
        }
}

// ---- dispatch 2: fused bucket-count + w-hat + GEMM. One block per 256-node tile.
// Reads its OWN tile region of out (scratch written by dispatch 1), then
// overwrites it with the final rows. No other block touches this region.
__global__ __launch_bounds__(256, 2) void rgcn_main(
    const float*  __restrict__ emb,      // fp32 [N][64]
    float*        out,                   // fp32 [N][64]; first 40960B/tile = scratch
    int N)
{
    __shared__ int    cnt[4608];      // 18 KB: per-key counts for this tile
    __shared__ float  wft[18][256];   // 18 KB: w-hat transposed
    __shared__ ushort wbL[256][32];   // 16 KB: bf16 w-hat (k-padded)

    const int t    = threadIdx.x;
    const int b    = blockIdx.x;
    const int wave = t >> 6;
    const int lane = t & 63;
    const int m    = lane & 15;
    const int q    = lane >> 4;
    const int rowbase = b * 256 + wave * 64;
    const int lrow    = wave * 64;

    #pragma unroll
    for (int i = t; i < 4608; i += 256) cnt[i] = 0;

    // A fragments + first weight prefetch before the barrier (global,
    // independent of LDS) so their latency overlaps phase-A setup
    shortx8 af[4][2];
    #pragma unroll
    for (int mt = 0; mt < 4; mt++) {
        int n = rowbase + mt * 16 + m;
        if (n >= N) n = N - 1;           // contribution zeroed via w-hat=0
        load_af(emb, n, q, af[mt]);
    }
    const ushort* wbase = &wt_g[0] + (size_t)lane * 8;

    __syncthreads();   // cnt zeroed

    // gather this tile's compacted segments (own region) + LDS histogram
    const ushort* reg = (const ushort*)((const char*)out + (size_t)b * 65536);
    #pragma unroll
    for (int w = t; w < NBUF; w += 256) {
        const ushort* seg = reg + w * SEGW;
        uint c = seg[SEGW - 1];
        const uint* sw = (const uint*)seg;
        for (uint wd = 0; wd < (c >> 1); wd++) {
            uint v = sw[wd];
            atomicAdd(&cnt[v & 0xffffu], 1);
            atomicAdd(&cnt[v >> 16], 1);
        }
        if (c & 1) atomicAdd(&cnt[seg[c - 1]], 1);
    }
    __syncthreads();   // histogram done (also drains all scratch reads)

    // per-node normalized relation weights (thread t <-> local node t)
    {
        int c[18]; int s = 0;
        #pragma unroll
        for (int r = 0; r < 18; r++) { c[r] = cnt[t * 18 + r]; s += c[r]; }
        float inv = (s > 0) ? (1.0f / (float)s) : 0.0f;
        #pragma unroll
        for (int r = 0; r < 18; r++) {
            float w = (float)c[r] * inv;
            wft[r][t] = w;
            wbL[t][r] = f32_to_bf16_rne(w);
        }
        #pragma unroll
        for (int r = 18; r < 32; r++) wbL[t][r] = 0;
    }
    __syncthreads();   // wft/wbL ready — last hard barrier

    gemm_store(af, wft, wbL, wbase, &bias_g[0], out, N, lrow, rowbase, m, q, lane);
}

// ---- fallback main: reads packed u8 counts (used only for odd shapes)
__global__ __launch_bounds__(256, 2) void rgcn_main_c8(
    const float*  __restrict__ emb,
    const uchar*  __restrict__ cnts8,    // [nbuckets][4608]
    const ushort* __restrict__ wt_sw,
    const ushort* __restrict__ bias_sw,
    float*        __restrict__ out,
    int N)
{
    __shared__ float  wft[18][256];
    __shared__ ushort wbL[256][32];
    __shared__ uchar  craw[4608];

    const int t    = threadIdx.x;
    const int wave = t >> 6;
    const int lane = t & 63;
    const int m    = lane & 15;
    const int q    = lane >> 4;
    const int rowbase = blockIdx.x * 256 + wave * 64;
    const int lrow    = wave * 64;

    {
        const uint* srcp = (const uint*)(cnts8 + (size_t)blockIdx.x * 4608);
        uint* d = (uint*)craw;
        #pragma unroll
        for (int i = t; i < 1152; i += 256) d[i] = srcp[i];
    }
    shortx8 af[4][2];
    #pragma unroll
    for (int mt = 0; mt < 4; mt++) {
        int n = rowbase + mt * 16 + m;
        if (n >= N) n = N - 1;
        load_af(emb, n, q, af[mt]);
    }
    const ushort* wbase = wt_sw + (size_t)lane * 8;
    __syncthreads();
    {
        int c[18]; int s = 0;
        const uchar* cp = &craw[t * 18];
        #pragma unroll
        for (int r = 0; r < 18; r++) { c[r] = cp[r]; s += c[r]; }
        float inv = (s > 0) ? (1.0f / (float)s) : 0.0f;
        #pragma unroll
        for (int r = 0; r < 18; r++) {
            float w = (float)c[r] * inv;
            wft[r][t] = w;
            wbL[t][r] = f32_to_bf16_rne(w);
        }
        #pragma unroll
        for (int r = 18; r < 32; r++) wbL[t][r] = 0;
    }
    __syncthreads();
    gemm_store(af, wft, wbL, wbase, bias_sw, out, N, lrow, rowbase, m, q, lane);
}

extern "C" void kernel_launch(void* const* d_in, const int* in_sizes, int n_in,
                              void* d_out, int out_size, void* d_ws, size_t ws_size,
                              hipStream_t stream) {
    const int*   edge_index = (const int*)d_in[0];     // [2][E] int32
    const int*   edge_type  = (const int*)d_in[1];     // [E]    int32
    const float* emb        = (const float*)d_in[2];   // [N][64]  fp32
    const float* weights    = (const float*)d_in[3];   // [3][18][64][64] fp32
    const float* biases     = (const float*)d_in[4];   // [3][18][64] fp32
    float* out = (float*)d_out;

    const int E = in_sizes[1];
    const int N = in_sizes[2] / 64;
    const int nbuckets = (N + 255) >> 8;               // 256-node tiles

    const float* w2 = weights + 2 * 18 * 64 * 64;      // only layer 2 is live
    const float* b2 = biases  + 2 * 18 * 64;

    // fast path needs: buckets fit the table AND the (possibly truncated)
    // last tile region holds its 512*80B of scratch. out_size is an element
    // count in this harness (in_sizes[] are element counts); use a
    // units-agnostic sanity check: N*64 <= out_size whether elements or bytes.
    const int lastrows = N - 256 * (nbuckets - 1);
    const bool fast = (nbuckets <= NBKT) &&
                      ((size_t)lastrows * 256 >= (size_t)NBUF * (SEGW * 2)) &&
                      ((size_t)out_size >= (size_t)N * 64);

    if (fast) {
        // ZERO workspace usage: scratch lives in d_out tile regions + device globals
        rgcn_scatter_prep<<<NBUF + PREPB, 256, 0, stream>>>(
            edge_index, edge_type, w2, b2, out, E, N, nbuckets);
        rgcn_main<<<nbuckets, 256, 0, stream>>>(emb, out, N);
    } else {
        // fallback: scattered atomics into i32, pack to u8, c8 main (ws-based)
        int* c32 = (int*)d_ws;
        uchar* cnts8 = (uchar*)((char*)d_ws + (((size_t)nbuckets * 4608 * 4 + 63) & ~(size_t)63));
        ushort* wt_sw   = (ushort*)(cnts8 + (size_t)nbuckets * 4608);
        ushort* bias_sw = wt_sw + 73728;
        rgcn_prep_k<<<(73728 + 2048 + 255) / 256, 256, 0, stream>>>(w2, b2, wt_sw, bias_sw);
        hipMemsetAsync(c32, 0, (size_t)nbuckets * 4608 * 4, stream);
        rgcn_count32<<<(E + 255) / 256, 256, 0, stream>>>(edge_index, edge_type, c32, E, N);
        int total4 = nbuckets * 4608 / 4;
        rgcn_cvt8<<<(total4 + 255) / 256, 256, 0, stream>>>(c32, cnts8, total4);
        rgcn_main_c8<<<nbuckets, 256, 0, stream>>>(emb, cnts8, wt_sw, bias_sw, out, N);
    }
}

// Round 3
// 124.492 us; speedup vs baseline: 1.5332x; 1.0021x over previous
//
#include <hip/hip_runtime.h>

// RGCN encoder, MI355X.  out[n] = sum_r (c[n][r]/cnt[n]) * (emb[n]@W2[r] + b2[r])
// (only layer-2 live; messages scatter to their own source node).
// Round-13: attack the histogram latency chains (ws-free structure kept from
// round-12; the 256MiB ws poison fill is unconditional+timed, ~42us of the
// 124.7us window; our two kernels ~= 82us vs ~15us BW roofline -> latency).
//   (1) main: bulk register-load of the tile's 40KB segment region (thread t
//       owns segs 2t,2t+1 = 10 x uint4, issued pre-barrier), histogram runs
//       from registers via statically-indexed template steps (no runtime
//       indexing -> no scratch; rule #20) with __any early-outs. Kills the
//       dependent cross-XCD load chains + divergent word loop.
//   (2) scatter: fixed-shape flush -- count embedded in LDS row, 5 x uint4
//       stores per segment (bins rows padded to 96B for b128 alignment).
//   (3) main: first weight buffer (bA) loaded before the histogram so the
//       cold wt_g miss hides under histogram work.
// GEMM r-loop (soft s_barrier L1-aligned weight streaming) unchanged.

typedef float  floatx4 __attribute__((ext_vector_type(4)));
typedef short  shortx8 __attribute__((ext_vector_type(8)));
typedef unsigned int uint;
typedef unsigned char uchar;

#define MFMA_BF16(A, B, C) __builtin_amdgcn_mfma_f32_16x16x32_bf16((A), (B), (C), 0, 0, 0)

#define NBUF 512        // scatter writer blocks
#define NBKT 512        // max buckets (391 used at N=100000)
#define CAP  38         // u16 entries per (writer,bucket); load ~Poisson(10), P(>38)~3e-12
#define SEGW 40         // ushort stride per segment: [0..37]=entries, [39]=count
#define BROW 48         // LDS bin row stride in u16 (96B, 16B-aligned for b128)
#define PREPB 19        // 18 weight-transpose blocks + 1 bias block

// module-static scratch: persists across iterations, rewritten every launch,
// NOT part of d_ws so the harness poison never touches it.
__device__ ushort wt_g[73728];   // bf16 [18][4096] fragment order
__device__ ushort bias_g[2048];  // bf16 fragment order

static __device__ __forceinline__ ushort f32_to_bf16_rne(float f) {
    union { float f; unsigned u; } v; v.f = f;
    unsigned r = v.u + 0x7fffu + ((v.u >> 16) & 1u);
    return (ushort)(r >> 16);
}

// ---- dispatch 1: scatter (blocks 0..NBUF) + prep (blocks NBUF..NBUF+PREPB)
// prep fragment layout: wt_g[r*4096 + d], d=(cid*64+lane)*8+j encodes
//   nt=cid>>1, kh=cid&1, o=nt*16+(lane&15), k=kh*32+(lane>>4)*8+j,
//   value = bf16(W2[r][k][o])
__global__ __launch_bounds__(256) void rgcn_scatter_prep(
    const int*   __restrict__ ei,       // [2][E]
    const int*   __restrict__ et,       // [E]
    const float* __restrict__ w2,       // fp32 [18][64][64]
    const float* __restrict__ b2,       // fp32 [18][64]
    float*       __restrict__ out,      // scratch target: tile-own regions
    int E, int N, int nbuckets)
{
    __shared__ uint   cur[NBKT];
    __shared__ ushort bins[NBKT][BROW];  // 48 KB (rows 16B-aligned; overlaid as wlds for prep)

    const int t = threadIdx.x;

    if (blockIdx.x >= NBUF) {            // ---- prep part -> device globals
        int pb = blockIdx.x - NBUF;
        ushort* wlds = &bins[0][0];      // reuse LDS: 4096 bf16 = 8 KB
        if (pb < 18) {
            // coalesced read of W2[pb] (4096 floats), bf16 into LDS at [k*64+o]
            const float* src = w2 + (pb << 12);
            #pragma unroll
            for (int i = 0; i < 16; i++) {
                int idx = t + 256 * i;
                wlds[idx] = f32_to_bf16_rne(src[idx]);
            }
            __syncthreads();
            // coalesced write: thread t emits d = t*16 .. t*16+15
            ushort* dst = wt_g + (pb << 12);
            #pragma unroll
            for (int u = 0; u < 16; u++) {
                int d = t * 16 + u;
                int cid  = d >> 9;
                int lane = (d >> 3) & 63;
                int j    = d & 7;
                int o = (cid >> 1) * 16 + (lane & 15);
                int k = (cid & 1) * 32 + (lane >> 4) * 8 + j;
                dst[d] = wlds[(k << 6) + o];
            }
        } else {
            // bias: bias_g[i2], o=nt*16+(lane&15), rr=(lane>>4)*8+j
            #pragma unroll
            for (int u = 0; u < 8; u++) {
                int i2 = t * 8 + u;
                int nt   = i2 >> 9;
                int lane = (i2 >> 3) & 63;
                int j    = i2 & 7;
                int o  = nt * 16 + (lane & 15);
                int rr = (lane >> 4) * 8 + j;
                bias_g[i2] = (rr < 18) ? f32_to_bf16_rne(b2[rr * 64 + o]) : (ushort)0;
            }
        }
        return;
    }

    // ---- scatter part
    #pragma unroll
    for (int b = t; b < NBKT; b += 256) cur[b] = 0;
    __syncthreads();

    const int epb = (E + NBUF - 1) / NBUF;
    const int e0 = blockIdx.x * epb;
    const int e1 = (e0 + epb < E) ? e0 + epb : E;

    for (int e = e0 + t; e < e1; e += 256) {
        int r = et[e]; int i0 = ei[e]; int i1 = ei[E + e];
        if ((unsigned)r < 9u) {
            if ((unsigned)i0 < (unsigned)N) {
                int b = i0 >> 8;
                uint o = atomicAdd(&cur[b], 1u);
                if (o < CAP) bins[b][o] = (ushort)((i0 & 255) * 18 + r);
            }
            if ((unsigned)i1 < (unsigned)N) {
                int b = i1 >> 8;
                uint o = atomicAdd(&cur[b], 1u);
                if (o < CAP) bins[b][o] = (ushort)((i1 & 255) * 18 + 9 + r);
            }
        }
    }
    __syncthreads();

    // fixed-shape flush into tile-own regions of out:
    //   seg(b,blk) = out + b*65536B + blk*80B ; entries [0..c-1], count at u16[39]
    //   count embedded in the LDS row, then 5 x uint4 copied (garbage beyond
    //   count is never read). Rows 96B -> aligned b128 LDS reads.
    const int blk = blockIdx.x;
    for (int b = t; b < nbuckets; b += 256) {
        uint c = cur[b];
        if (c > CAP) c = CAP;
        bins[b][SEGW - 1] = (ushort)c;
        const uint4* srow = (const uint4*)&bins[b][0];
        uint4* dst = (uint4*)((char*)out + (size_t)b * 65536 + (size_t)blk * (SEGW * 2));
        #pragma unroll
        for (int j = 0; j < 5; j++) dst[j] = srow[j];
    }
}

// ---- fallback path kernels (shape doesn't fit tile-own scratch): ws-based
__global__ void rgcn_prep_k(const float* __restrict__ w2, const float* __restrict__ b2,
                            ushort* __restrict__ wt_sw, ushort* __restrict__ bias_sw) {
    int i = blockIdx.x * 256 + threadIdx.x;
    const int WELEMS = 18 * 8 * 64 * 8;
    if (i < WELEMS) {
        int r    = i >> 12;
        int rem  = i & 4095;
        int cid  = rem >> 9;
        int lane = (rem >> 3) & 63;
        int j    = i & 7;
        int nt = cid >> 1, kh = cid & 1;
        int o = nt * 16 + (lane & 15);
        int k = kh * 32 + (lane >> 4) * 8 + j;
        wt_sw[i] = f32_to_bf16_rne(w2[(r << 12) + (k << 6) + o]);
    } else {
        int i2 = i - WELEMS;
        if (i2 < 2048) {
            int nt   = i2 >> 9;
            int lane = (i2 >> 3) & 63;
            int j    = i2 & 7;
            int o  = nt * 16 + (lane & 15);
            int rr = (lane >> 4) * 8 + j;
            bias_sw[i2] = (rr < 18) ? f32_to_bf16_rne(b2[rr * 64 + o]) : (ushort)0;
        }
    }
}
__global__ void rgcn_count32(const int* __restrict__ ei, const int* __restrict__ et,
                             int* __restrict__ cnts, int E, int N) {
    int e = blockIdx.x * 256 + threadIdx.x;
    if (e < E) {
        int r = et[e];
        int i0 = ei[e];
        int i1 = ei[E + e];
        if ((unsigned)r < 9u) {
            if ((unsigned)i0 < (unsigned)N) atomicAdd(&cnts[i0 * 18 + r], 1);
            if ((unsigned)i1 < (unsigned)N) atomicAdd(&cnts[i1 * 18 + 9 + r], 1);
        }
    }
}
__global__ void rgcn_cvt8(const int* __restrict__ c32, uchar* __restrict__ c8, int total4) {
    int i = blockIdx.x * 256 + threadIdx.x;
    if (i < total4) {
        uint v = 0;
        #pragma unroll
        for (int j = 0; j < 4; j++) {
            int c = c32[i * 4 + j];
            if (c > 255) c = 255;
            v |= ((uint)c) << (8 * j);
        }
        ((uint*)c8)[i] = v;
    }
}

static __device__ __forceinline__ void load_af(
    const float* __restrict__ emb, int n, int q, shortx8 af[2])
{
    const float* rp = emb + (size_t)n * 64 + q * 8;
    #pragma unroll
    for (int kh = 0; kh < 2; kh++) {
        floatx4 lo = *(const floatx4*)(rp + kh * 32);
        floatx4 hi = *(const floatx4*)(rp + kh * 32 + 4);
        shortx8 f;
        #pragma unroll
        for (int j = 0; j < 4; j++) {
            f[j]     = (short)f32_to_bf16_rne(lo[j]);
            f[j + 4] = (short)f32_to_bf16_rne(hi[j]);
        }
        af[kh] = f;
    }
}

// one statically-indexed histogram step: processes u16 entries 2W,2W+1 of both
// register-resident segments (seg0 = U[0..4], seg1 = U[5..9]); W compile-time
// so all U accesses are constant-indexed (no scratch).
template<int W>
static __device__ __forceinline__ void hstep(const uint4 (&U)[10], uint c0, uint c1, int* cnt) {
    constexpr int q0 = W >> 2, r0 = W & 3;
    constexpr int w1 = W + 20;
    constexpr int q1 = w1 >> 2, r1 = w1 & 3;
    uint v0 = (r0 == 0) ? U[q0].x : (r0 == 1) ? U[q0].y : (r0 == 2) ? U[q0].z : U[q0].w;
    uint v1 = (r1 == 0) ? U[q1].x : (r1 == 1) ? U[q1].y : (r1 == 2) ? U[q1].z : U[q1].w;
    if (2 * W     < (int)c0) atomicAdd(&cnt[v0 & 0xffffu], 1);
    if (2 * W + 1 < (int)c0) atomicAdd(&cnt[v0 >> 16], 1);
    if (2 * W     < (int)c1) atomicAdd(&cnt[v1 & 0xffffu], 1);
    if (2 * W + 1 < (int)c1) atomicAdd(&cnt[v1 >> 16], 1);
}

// shared GEMM tail: r-loop with SOFT wave-alignment barriers + bias MFMA + store
// bA_in: first weight buffer, preloaded by caller (hoisted above histogram).
static __device__ __forceinline__ void gemm_store(
    const shortx8 af[4][2],
    const shortx8 bA_in[8],
    const float  (*__restrict__ wft)[256],
    const ushort (*__restrict__ wbL)[32],
    const ushort* __restrict__ wbase,
    const ushort* __restrict__ bias_p,
    float* __restrict__ out, int N,
    int lrow, int rowbase, int m, int q, int lane)
{
    shortx8 bA[8], bB[8];
    #pragma unroll
    for (int c = 0; c < 8; c++) bA[c] = bA_in[c];

    floatx4 acc[4][4];
    #pragma unroll
    for (int mt = 0; mt < 4; mt++)
        #pragma unroll
        for (int nt = 0; nt < 4; nt++)
            acc[mt][nt] = (floatx4){0.f, 0.f, 0.f, 0.f};

    for (int r = 0; r < 18; r += 2) {
        // SOFT barrier: bare s_barrier (no waitcnt drain) — aligns the 4 waves
        // so they stream the same 8KB/r weight chunk through L1 together.
        __builtin_amdgcn_s_barrier();
        {   // prefetch r+1
            const ushort* p = wbase + (size_t)(r + 1) * 4096;
            #pragma unroll
            for (int c = 0; c < 8; c++) bB[c] = *(const shortx8*)(p + c * 512);
        }
        {   // compute r
            floatx4 swv[4];
            #pragma unroll
            for (int mt = 0; mt < 4; mt++)
                swv[mt] = *(const floatx4*)&wft[r][lrow + mt * 16 + q * 4];
            #pragma unroll
            for (int nt = 0; nt < 4; nt++)
                #pragma unroll
                for (int mt = 0; mt < 4; mt++) {
                    floatx4 tmp = (floatx4){0.f, 0.f, 0.f, 0.f};
                    tmp = MFMA_BF16(af[mt][0], bA[nt * 2 + 0], tmp);
                    tmp = MFMA_BF16(af[mt][1], bA[nt * 2 + 1], tmp);
                    acc[mt][nt] += swv[mt] * tmp;
                }
        }
        if (r + 2 < 18) {   // prefetch r+2
            const ushort* p = wbase + (size_t)(r + 2) * 4096;
            #pragma unroll
            for (int c = 0; c < 8; c++) bA[c] = *(const shortx8*)(p + c * 512);
        }
        {   // compute r+1
            floatx4 swv[4];
            #pragma unroll
            for (int mt = 0; mt < 4; mt++)
                swv[mt] = *(const floatx4*)&wft[r + 1][lrow + mt * 16 + q * 4];
            #pragma unroll
            for (int nt = 0; nt < 4; nt++)
                #pragma unroll
                for (int mt = 0; mt < 4; mt++) {
                    floatx4 tmp = (floatx4){0.f, 0.f, 0.f, 0.f};
                    tmp = MFMA_BF16(af[mt][0], bB[nt * 2 + 0], tmp);
                    tmp = MFMA_BF16(af[mt][1], bB[nt * 2 + 1], tmp);
                    acc[mt][nt] += swv[mt] * tmp;
                }
        }
    }

    // bias MFMA: A = w-hat bf16 rows (K=32), B = bias fragments
    #pragma unroll
    for (int nt = 0; nt < 4; nt++) {
        shortx8 btf = *(const shortx8*)(bias_p + ((size_t)nt * 64 + lane) * 8);
        #pragma unroll
        for (int mt = 0; mt < 4; mt++) {
            shortx8 wfrag = *(const shortx8*)&wbL[lrow + mt * 16 + m][q * 8];
            acc[mt][nt] = MFMA_BF16(wfrag, btf, acc[mt][nt]);
        }
    }

    // store; D layout col = nt*16+m, row = q*4+i
    #pragma unroll
    for (int mt = 0; mt < 4; mt++)
        #pragma unroll
        for (int i = 0; i < 4; i++) {
            int nn = rowbase + mt * 16 + q * 4 + i;
            if (nn < N) {
                #pragma unroll
                for (int nt = 0; nt < 4; nt++)
                    out[(size_t)nn * 64 + nt * 16 + m] = acc[mt][nt][i];
            }
        }
}

// ---- dispatch 2: fused bucket-count + w-hat + GEMM. One block per 256-node tile.
// Reads its OWN tile region of out (scratch written by dispatch 1) via bulk
// register loads, then overwrites it with the final rows (ordered by the
// histogram barrier). No other block touches this region.
__global__ __launch_bounds__(256, 2) void rgcn_main(
    const float*  __restrict__ emb,      // fp32 [N][64]
    float*        out,                   // fp32 [N][64]; first 40960B/tile = scratch
    int N)
{
    __shared__ int    cnt[4608];      // 18 KB: per-key counts for this tile
    __shared__ float  wft[18][256];   // 18 KB: w-hat transposed
    __shared__ ushort wbL[256][32];   // 16 KB: bf16 w-hat (k-padded)

    const int t    = threadIdx.x;
    const int b    = blockIdx.x;
    const int wave = t >> 6;
    const int lane = t & 63;
    const int m    = lane & 15;
    const int q    = lane >> 4;
    const int rowbase = b * 256 + wave * 64;
    const int lrow    = wave * 64;

    // bulk-load this tile's 40KB segment region: thread t owns segs 2t,2t+1
    // (10 x uint4, independent loads, issued before any barrier)
    const uint4* R4 = (const uint4*)((const char*)out + (size_t)b * 65536);
    uint4 U[10];
    #pragma unroll
    for (int j = 0; j < 10; j++) U[j] = R4[t * 10 + j];

    #pragma unroll
    for (int i = t; i < 4608; i += 256) cnt[i] = 0;

    // A fragments + first weight buffer before the barrier (global, independent
    // of LDS) so their latency overlaps LDS init + histogram
    shortx8 af[4][2];
    #pragma unroll
    for (int mt = 0; mt < 4; mt++) {
        int n = rowbase + mt * 16 + m;
        if (n >= N) n = N - 1;           // contribution zeroed via w-hat=0
        load_af(emb, n, q, af[mt]);
    }
    const ushort* wbase = &wt_g[0] + (size_t)lane * 8;
    shortx8 bA0[8];
    #pragma unroll
    for (int c = 0; c < 8; c++) bA0[c] = *(const shortx8*)(wbase + c * 512);

    __syncthreads();   // cnt zeroed

    // register-resident histogram: counts at u16 #39 of each segment
    {
        uint c0 = U[4].w >> 16;
        uint c1 = U[9].w >> 16;
        uint cm = c0 > c1 ? c0 : c1;
        hstep<0>(U, c0, c1, cnt); hstep<1>(U, c0, c1, cnt);
        hstep<2>(U, c0, c1, cnt); hstep<3>(U, c0, c1, cnt); hstep<4>(U, c0, c1, cnt);
        if (__any((int)cm > 10)) {
            hstep<5>(U, c0, c1, cnt); hstep<6>(U, c0, c1, cnt);
            if (__any((int)cm > 14)) {
                hstep<7>(U, c0, c1, cnt); hstep<8>(U, c0, c1, cnt);
                if (__any((int)cm > 18)) {
                    hstep<9>(U, c0, c1, cnt); hstep<10>(U, c0, c1, cnt); hstep<11>(U, c0, c1, cnt);
                    if (__any((int)cm > 24)) {
                        hstep<12>(U, c0, c1, cnt); hstep<13>(U, c0, c1, cnt); hstep<14>(U, c0, c1, cnt);
                        if (__any((int)cm > 30)) {
                            hstep<15>(U, c0, c1, cnt); hstep<16>(U, c0, c1, cnt);
                            hstep<17>(U, c0, c1, cnt); hstep<18>(U, c0, c1, cnt);
                        }
                    }
                }
            }
        }
    }
    __syncthreads();   // histogram done (all scratch reads complete before any store)

    // per-node normalized relation weights (thread t <-> local node t)
    {
        int c[18]; int s = 0;
        #pragma unroll
        for (int r = 0; r < 18; r++) { c[r] = cnt[t * 18 + r]; s += c[r]; }
        float inv = (s > 0) ? (1.0f / (float)s) : 0.0f;
        #pragma unroll
        for (int r = 0; r < 18; r++) {
            float w = (float)c[r] * inv;
            wft[r][t] = w;
            wbL[t][r] = f32_to_bf16_rne(w);
        }
        #pragma unroll
        for (int r = 18; r < 32; r++) wbL[t][r] = 0;
    }
    __syncthreads();   // wft/wbL ready — last hard barrier

    gemm_store(af, bA0, wft, wbL, wbase, &bias_g[0], out, N, lrow, rowbase, m, q, lane);
}

// ---- fallback main: reads packed u8 counts (used only for odd shapes)
__global__ __launch_bounds__(256, 2) void rgcn_main_c8(
    const float*  __restrict__ emb,
    const uchar*  __restrict__ cnts8,    // [nbuckets][4608]
    const ushort* __restrict__ wt_sw,
    const ushort* __restrict__ bias_sw,
    float*        __restrict__ out,
    int N)
{
    __shared__ float  wft[18][256];
    __shared__ ushort wbL[256][32];
    __shared__ uchar  craw[4608];

    const int t    = threadIdx.x;
    const int wave = t >> 6;
    const int lane = t & 63;
    const int m    = lane & 15;
    const int q    = lane >> 4;
    const int rowbase = blockIdx.x * 256 + wave * 64;
    const int lrow    = wave * 64;

    {
        const uint* srcp = (const uint*)(cnts8 + (size_t)blockIdx.x * 4608);
        uint* d = (uint*)craw;
        #pragma unroll
        for (int i = t; i < 1152; i += 256) d[i] = srcp[i];
    }
    shortx8 af[4][2];
    #pragma unroll
    for (int mt = 0; mt < 4; mt++) {
        int n = rowbase + mt * 16 + m;
        if (n >= N) n = N - 1;
        load_af(emb, n, q, af[mt]);
    }
    const ushort* wbase = wt_sw + (size_t)lane * 8;
    shortx8 bA0[8];
    #pragma unroll
    for (int c = 0; c < 8; c++) bA0[c] = *(const shortx8*)(wbase + c * 512);
    __syncthreads();
    {
        int c[18]; int s = 0;
        const uchar* cp = &craw[t * 18];
        #pragma unroll
        for (int r = 0; r < 18; r++) { c[r] = cp[r]; s += c[r]; }
        float inv = (s > 0) ? (1.0f / (float)s) : 0.0f;
        #pragma unroll
        for (int r = 0; r < 18; r++) {
            float w = (float)c[r] * inv;
            wft[r][t] = w;
            wbL[t][r] = f32_to_bf16_rne(w);
        }
        #pragma unroll
        for (int r = 18; r < 32; r++) wbL[t][r] = 0;
    }
    __syncthreads();
    gemm_store(af, bA0, wft, wbL, wbase, bias_sw, out, N, lrow, rowbase, m, q, lane);
}

extern "C" void kernel_launch(void* const* d_in, const int* in_sizes, int n_in,
                              void* d_out, int out_size, void* d_ws, size_t ws_size,
                              hipStream_t stream) {
    const int*   edge_index = (const int*)d_in[0];     // [2][E] int32
    const int*   edge_type  = (const int*)d_in[1];     // [E]    int32
    const float* emb        = (const float*)d_in[2];   // [N][64]  fp32
    const float* weights    = (const float*)d_in[3];   // [3][18][64][64] fp32
    const float* biases     = (const float*)d_in[4];   // [3][18][64] fp32
    float* out = (float*)d_out;

    const int E = in_sizes[1];
    const int N = in_sizes[2] / 64;
    const int nbuckets = (N + 255) >> 8;               // 256-node tiles

    const float* w2 = weights + 2 * 18 * 64 * 64;      // only layer 2 is live
    const float* b2 = biases  + 2 * 18 * 64;

    // fast path needs: buckets fit the table AND the (possibly truncated)
    // last tile region holds its 512*80B of scratch. out_size is an element
    // count in this harness (in_sizes[] are element counts); use a
    // units-agnostic sanity check: N*64 <= out_size whether elements or bytes.
    const int lastrows = N - 256 * (nbuckets - 1);
    const bool fast = (nbuckets <= NBKT) &&
                      ((size_t)lastrows * 256 >= (size_t)NBUF * (SEGW * 2)) &&
                      ((size_t)out_size >= (size_t)N * 64);

    if (fast) {
        // ZERO workspace usage: scratch lives in d_out tile regions + device globals
        rgcn_scatter_prep<<<NBUF + PREPB, 256, 0, stream>>>(
            edge_index, edge_type, w2, b2, out, E, N, nbuckets);
        rgcn_main<<<nbuckets, 256, 0, stream>>>(emb, out, N);
    } else {
        // fallback: scattered atomics into i32, pack to u8, c8 main (ws-based)
        int* c32 = (int*)d_ws;
        uchar* cnts8 = (uchar*)((char*)d_ws + (((size_t)nbuckets * 4608 * 4 + 63) & ~(size_t)63));
        ushort* wt_sw   = (ushort*)(cnts8 + (size_t)nbuckets * 4608);
        ushort* bias_sw = wt_sw + 73728;
        rgcn_prep_k<<<(73728 + 2048 + 255) / 256, 256, 0, stream>>>(w2, b2, wt_sw, bias_sw);
        hipMemsetAsync(c32, 0, (size_t)nbuckets * 4608 * 4, stream);
        rgcn_count32<<<(E + 255) / 256, 256, 0, stream>>>(edge_index, edge_type, c32, E, N);
        int total4 = nbuckets * 4608 / 4;
        rgcn_cvt8<<<(total4 + 255) / 256, 256, 0, stream>>>(c32, cnts8, total4);
        rgcn_main_c8<<<nbuckets, 256, 0, stream>>>(emb, cnts8, wt_sw, bias_sw, out, N);
    }
}